// Round 6
// baseline (1259.936 us; speedup 1.0000x reference)
//
#include <hip/hip_runtime.h>
#include <hip/hip_bf16.h>

// GraphUpsampler: N=4096 -> M=8192 dense GCN, 3 iters, out = sigmoid(Xu@Xu.T) f32 [8192,8192].
// R6: Adj stored TILE-MAJOR ([tm][tn][128][128], 32KB contiguous tiles) +
//     barrier-free direct-to-VGPR aggregation (R4 literal ping-pong, no LDS/no barriers).
//     Tile-major makes BOTH the rebuild writes and the agg reads page-dense.

#define N_NODES 4096
#define M_NODES 8192
#define DIM 128
#define SLICE_ELEMS ((size_t)M_NODES * DIM)

typedef __attribute__((ext_vector_type(4))) float f32x4;
typedef __attribute__((ext_vector_type(8))) short bf16x8;

__device__ __forceinline__ unsigned short f2bf(float f) {
  union { float f; unsigned u; } v; v.f = f;
  unsigned r = v.u + 0x7fffu + ((v.u >> 16) & 1u);
  return (unsigned short)(r >> 16);
}

__device__ __forceinline__ void gld16(unsigned short* lds, const unsigned short* g) {
  __builtin_amdgcn_global_load_lds(
      (const __attribute__((address_space(1))) unsigned int*)g,
      (__attribute__((address_space(3))) unsigned int*)lds, 16, 0, 0);
}

__device__ __forceinline__ float sigmoidf_(float x) { return 1.0f / (1.0f + __expf(-x)); }

// ---------------- cast / init kernels ----------------

__global__ void cast_x_kernel(const float* __restrict__ X, unsigned short* __restrict__ Xu,
                              unsigned short* __restrict__ XT) {
  int idx = blockIdx.x * 256 + threadIdx.x;          // N*DIM
  int i = idx >> 7, c = idx & 127;
  unsigned short b = f2bf(X[idx]);
  Xu[idx] = b;
  XT[(size_t)c * N_NODES + i] = b;                   // X^T [128][4096]
}

// W_up f32 [4096][4096] -> bf16 tile-major (32 col-tiles)
__global__ void cast_wup_kernel(const float4* __restrict__ W, unsigned short* __restrict__ Wb) {
  int idx4 = blockIdx.x * 256 + threadIdx.x;         // N*N/4
  int r = idx4 >> 10, c = (idx4 & 1023) << 2;
  float4 v = W[idx4];
  ushort4 o;
  o.x = f2bf(v.x); o.y = f2bf(v.y); o.z = f2bf(v.z); o.w = f2bf(v.w);
  *(ushort4*)&Wb[((size_t)(r >> 7) * 32 + (c >> 7)) * 16384 + (r & 127) * 128 + (c & 127)] = o;
}

__global__ void cast_wt_kernel(const float* __restrict__ W, unsigned short* __restrict__ WT) {
  int idx = blockIdx.x * 256 + threadIdx.x;          // 128*128
  int k = idx >> 7, c = idx & 127;
  WT[c * DIM + k] = f2bf(W[idx]);                    // W^T [out][in]
}

// A f32 -> 3 blocks of tile-major Adj ([[A,A],[A,.]], A symmetric) + colsum(A)
__global__ void cast_a_kernel(const float* __restrict__ A, unsigned short* __restrict__ Adj,
                              float* __restrict__ colsumA) {
  int c = blockIdx.x * 256 + threadIdx.x;            // 0..4095
  int r0 = blockIdx.y * 128;
  int tm = r0 >> 7, tc = c >> 7, cl = c & 127;
  size_t a1 = ((size_t)tm        * 64 + tc)      * 16384 + cl;  // (r, c)
  size_t a2 = ((size_t)tm        * 64 + 32 + tc) * 16384 + cl;  // (r, 4096+c)
  size_t a3 = ((size_t)(tm + 32) * 64 + tc)      * 16384 + cl;  // (4096+r, c)
  float s = 0.f;
  for (int r = 0; r < 128; ++r) {
    float a = A[(size_t)(r0 + r) * N_NODES + c];
    unsigned short b = f2bf(a);
    Adj[a1 + r * 128] = b; Adj[a2 + r * 128] = b; Adj[a3 + r * 128] = b;
    s += a;
  }
  atomicAdd(&colsumA[c], s);
}

__global__ void init_deg_kernel(const float* __restrict__ colsumA, float* __restrict__ deg) {
  int i = blockIdx.x * 256 + threadIdx.x;            // 8192
  deg[i] = (i < N_NODES) ? 2.0f * colsumA[i] : colsumA[i - N_NODES];
}

// ---------------- barrier-free streaming split-K aggregation ----------------
// C_partial[slice by] = At(tile-major)[row-tile bx][k-chunk by] @ B (BT[128 n][ldb k]).
// Direct global->VGPR literal ping-pong fragments; no LDS, no barriers.

__global__ __launch_bounds__(256, 2)
void agg_kernel(const unsigned short* __restrict__ At, int tnTotal,
                const unsigned short* __restrict__ BT, long ldb,
                float* __restrict__ accBase, int kIters) {
  const int t = threadIdx.x, w = t >> 6, lane = t & 63;
  const int q = lane >> 4, l15 = lane & 15;
  const int tn0 = blockIdx.y * (kIters >> 2);

  f32x4 acc[2][8];
#pragma unroll
  for (int a = 0; a < 2; ++a)
#pragma unroll
    for (int b = 0; b < 8; ++b) acc[a][b] = (f32x4)0.f;

  const size_t abase = ((size_t)blockIdx.x * tnTotal + tn0) * 16384 +
                       (size_t)(w * 32 + l15) * 128 + q * 8;
  const size_t bbase = (size_t)blockIdx.y * kIters * 32 + q * 8;

  bf16x8 a0_0, a1_0, b_0[8];
  bf16x8 a0_1, a1_1, b_1[8];

#define LOADG(KT, S)                                                                \
  do {                                                                              \
    const int kt_ = (KT);                                                           \
    const size_t ao_ = (size_t)(kt_ >> 2) * 16384 + (kt_ & 3) * 32;                 \
    a0_##S = *(const bf16x8*)&At[abase + ao_];                                      \
    a1_##S = *(const bf16x8*)&At[abase + 16 * 128 + ao_];                           \
    _Pragma("unroll")                                                               \
    for (int nt = 0; nt < 8; ++nt)                                                  \
      b_##S[nt] = *(const bf16x8*)&BT[(size_t)(nt * 16 + l15) * ldb + bbase + (size_t)kt_ * 32]; \
  } while (0)

#define COMPUTE(S)                                                                  \
  do {                                                                              \
    _Pragma("unroll")                                                               \
    for (int nt = 0; nt < 8; ++nt) {                                                \
      acc[0][nt] = __builtin_amdgcn_mfma_f32_16x16x32_bf16(a0_##S, b_##S[nt], acc[0][nt], 0, 0, 0); \
      acc[1][nt] = __builtin_amdgcn_mfma_f32_16x16x32_bf16(a1_##S, b_##S[nt], acc[1][nt], 0, 0, 0); \
    }                                                                               \
  } while (0)

  LOADG(0, 0);
  int kt = 0;
#pragma unroll 1
  for (; kt + 2 < kIters; kt += 2) {
    LOADG(kt + 1, 1);
    COMPUTE(0);
    LOADG(kt + 2, 0);
    COMPUTE(1);
  }
  LOADG(kt + 1, 1);
  COMPUTE(0);
  COMPUTE(1);
#undef LOADG
#undef COMPUTE

  // packed C: 16B/lane fully coalesced
  float* ct = accBase + (size_t)blockIdx.y * SLICE_ELEMS + (size_t)blockIdx.x * 16384;
#pragma unroll
  for (int mt = 0; mt < 2; ++mt)
#pragma unroll
    for (int nt = 0; nt < 8; ++nt)
      *(f32x4*)&ct[(((w * 2 + mt) * 8 + nt) * 256) + (q * 16 + l15) * 4] = acc[mt][nt];
}

// sum packed partials + epilogue -> bf16 row-major
// mode 0: v = s + bias_row[row];  mode 1: v = relu(rsqrt(deg[row])*s + bias_col[col])
__global__ void reduce_acc_kernel(const float* __restrict__ acc,
                                  unsigned short* __restrict__ dst,
                                  const float* __restrict__ bias_row,
                                  const float* __restrict__ bias_col,
                                  const float* __restrict__ deg, int mode, int nSlices) {
  int p = blockIdx.x * 256 + threadIdx.x;
  float s = 0.f;
  for (int sp = 0; sp < nSlices; ++sp) s += acc[(size_t)sp * SLICE_ELEMS + p];
  int tile = p >> 14, r = p & 16383;
  int grp = r >> 8, r2 = r & 255;
  int nt = grp & 7, wmt = grp >> 3;
  int i = r2 & 3, ql = r2 >> 2;
  int row = tile * 128 + (wmt >> 1) * 32 + (wmt & 1) * 16 + (ql >> 4) * 4 + i;
  int col = nt * 16 + (ql & 15);
  float v;
  if (mode == 0) v = s + bias_row[row];
  else {
    float d = deg[row];
    float dv = d > 0.f ? rsqrtf(d) : 0.f;
    v = fmaxf(dv * s + bias_col[col], 0.f);
  }
  dst[(size_t)row * DIM + col] = f2bf(v);
}

// ---------------- rebuild: out = sigmoid(XA @ XB^T), K=128 ----------------
// MODE 0: bf16 tile-major out (TN=64) + fused col-sums into deg.  MODE 1: f32 row-major (final).

template <int MODE>
__global__ __launch_bounds__(256)
void rebuild_kernel(const unsigned short* __restrict__ XA,
                    const unsigned short* __restrict__ XB,
                    void* __restrict__ out, long p1 /*MODE0:row0, MODE1:ldo*/,
                    long col0, float* __restrict__ deg) {
  __shared__ __align__(16) unsigned short smem[32768];   // 64KB
  __shared__ float lcol[128];
  unsigned short* lA = smem;
  unsigned short* lB = smem + 16384;
  const int t = threadIdx.x, w = t >> 6, lane = t & 63;
  const int q = lane >> 4, l15 = lane & 15;
  const int i0 = blockIdx.x * 128, j0 = blockIdx.y * 128;
  const int srow = t >> 2, schk = t & 3;
#pragma unroll
  for (int kk = 0; kk < 4; ++kk)
#pragma unroll
    for (int h = 0; h < 2; ++h) {
      gld16(&lA[kk * 4096 + h * 2048 + t * 8],
            &XA[(size_t)(i0 + h * 64 + srow) * DIM + kk * 32 + schk * 8]);
      gld16(&lB[kk * 4096 + h * 2048 + t * 8],
            &XB[(size_t)(j0 + h * 64 + srow) * DIM + kk * 32 + schk * 8]);
    }
  if (MODE == 0 && t < 128) lcol[t] = 0.f;
  __syncthreads();

  f32x4 acc[2][8];
#pragma unroll
  for (int a = 0; a < 2; ++a)
#pragma unroll
    for (int b = 0; b < 8; ++b) acc[a][b] = (f32x4)0.f;

#pragma unroll
  for (int kk = 0; kk < 4; ++kk) {
    bf16x8 a0 = *(const bf16x8*)&lA[kk * 4096 + (w * 32 + l15) * 32 + q * 8];
    bf16x8 a1 = *(const bf16x8*)&lA[kk * 4096 + (w * 32 + 16 + l15) * 32 + q * 8];
#pragma unroll
    for (int nt = 0; nt < 8; ++nt) {
      bf16x8 b = *(const bf16x8*)&lB[kk * 4096 + (nt * 16 + l15) * 32 + q * 8];
      acc[0][nt] = __builtin_amdgcn_mfma_f32_16x16x32_bf16(a0, b, acc[0][nt], 0, 0, 0);
      acc[1][nt] = __builtin_amdgcn_mfma_f32_16x16x32_bf16(a1, b, acc[1][nt], 0, 0, 0);
    }
  }
  __syncthreads();   // staging reads done; smem reusable

  if (MODE == 0) {
    unsigned short* lC = smem;   // [128][136] bf16
#pragma unroll
    for (int mt = 0; mt < 2; ++mt)
#pragma unroll
      for (int nt = 0; nt < 8; ++nt) {
        float cs = 0.f;
#pragma unroll
        for (int i = 0; i < 4; ++i) {
          float sv = sigmoidf_(acc[mt][nt][i]);
          cs += sv;
          lC[(w * 32 + mt * 16 + q * 4 + i) * 136 + nt * 16 + l15] = f2bf(sv);
        }
        cs += __shfl_xor(cs, 16);
        cs += __shfl_xor(cs, 32);
        if (lane < 16) atomicAdd(&lcol[nt * 16 + lane], cs);
      }
    __syncthreads();
    // tile-major store: one contiguous 32KB tile per block
    unsigned short* og = (unsigned short*)out;
    const long rowbase = p1 + i0, colbase = col0 + j0;
    unsigned short* tg = og + (((size_t)(rowbase >> 7)) * 64 + (colbase >> 7)) * 16384;
#pragma unroll
    for (int cc = 0; cc < 8; ++cc) {
      int ch = t + cc * 256;                     // 0..2047
      int row = ch >> 4, c16 = ch & 15;
      *(bf16x8*)&tg[row * 128 + c16 * 8] = *(const bf16x8*)&lC[row * 136 + c16 * 8];
    }
    if (t < 128) atomicAdd(&deg[colbase + t], lcol[t]);
  } else {
    float* og = (float*)out;
    float* lCf = (float*)smem;                   // [64][128] f32 = 32KB
#pragma unroll
    for (int h2 = 0; h2 < 2; ++h2) {
      __syncthreads();
      if ((w >> 1) == h2) {
#pragma unroll
        for (int mt = 0; mt < 2; ++mt)
#pragma unroll
          for (int nt = 0; nt < 8; ++nt)
#pragma unroll
            for (int i = 0; i < 4; ++i)
              lCf[((w & 1) * 32 + mt * 16 + q * 4 + i) * 128 + nt * 16 + l15] =
                  sigmoidf_(acc[mt][nt][i]);
      }
      __syncthreads();
#pragma unroll
      for (int j = 0; j < 8; ++j) {
        int ch = t + j * 256;                    // f32x4 units
        int r64 = ch >> 5, c4 = (ch & 31) * 4;
        *(f32x4*)&og[(size_t)(i0 + h2 * 64 + r64) * p1 + j0 + c4] =
            *(const f32x4*)&lCf[r64 * 128 + c4];
      }
    }
  }
}

// ---------------- Z^T = (rsqrt(deg) ⊙ (Xu @ W)) transposed, [128][8192] ----------------

__global__ __launch_bounds__(256)
void yz_kernel(const unsigned short* __restrict__ Xu, const unsigned short* __restrict__ WT,
               const float* __restrict__ deg, unsigned short* __restrict__ ZT, int ldz) {
  __shared__ __align__(16) unsigned short smem[32768];
  unsigned short* lA = smem;
  unsigned short* lB = smem + 16384;
  const int t = threadIdx.x, w = t >> 6, lane = t & 63;
  const int q = lane >> 4, l15 = lane & 15;
  const int r0 = blockIdx.x * 128;
  const int srow = t >> 2, schk = t & 3;
#pragma unroll
  for (int kk = 0; kk < 4; ++kk)
#pragma unroll
    for (int h = 0; h < 2; ++h) {
      gld16(&lA[kk * 4096 + h * 2048 + t * 8],
            &Xu[(size_t)(r0 + h * 64 + srow) * DIM + kk * 32 + schk * 8]);
      gld16(&lB[kk * 4096 + h * 2048 + t * 8],
            &WT[(size_t)(h * 64 + srow) * DIM + kk * 32 + schk * 8]);
    }
  __syncthreads();

  f32x4 acc[2][8];
#pragma unroll
  for (int a = 0; a < 2; ++a)
#pragma unroll
    for (int b = 0; b < 8; ++b) acc[a][b] = (f32x4)0.f;

#pragma unroll
  for (int kk = 0; kk < 4; ++kk) {
    bf16x8 a0 = *(const bf16x8*)&lA[kk * 4096 + (w * 32 + l15) * 32 + q * 8];
    bf16x8 a1 = *(const bf16x8*)&lA[kk * 4096 + (w * 32 + 16 + l15) * 32 + q * 8];
#pragma unroll
    for (int nt = 0; nt < 8; ++nt) {
      bf16x8 b = *(const bf16x8*)&lB[kk * 4096 + (nt * 16 + l15) * 32 + q * 8];
      acc[0][nt] = __builtin_amdgcn_mfma_f32_16x16x32_bf16(a0, b, acc[0][nt], 0, 0, 0);
      acc[1][nt] = __builtin_amdgcn_mfma_f32_16x16x32_bf16(a1, b, acc[1][nt], 0, 0, 0);
    }
  }
  // per-thread dinv for its 8 rows
  float dv[2][4];
#pragma unroll
  for (int mt = 0; mt < 2; ++mt)
#pragma unroll
    for (int i = 0; i < 4; ++i) {
      float d = deg[r0 + w * 32 + mt * 16 + q * 4 + i];
      dv[mt][i] = d > 0.f ? rsqrtf(d) : 0.f;
    }
  __syncthreads();
  unsigned short* lT = smem;   // [c 128][r 136]
#pragma unroll
  for (int mt = 0; mt < 2; ++mt)
#pragma unroll
    for (int nt = 0; nt < 8; ++nt)
#pragma unroll
      for (int i = 0; i < 4; ++i) {
        int r = w * 32 + mt * 16 + q * 4 + i;
        lT[(nt * 16 + l15) * 136 + r] = f2bf(dv[mt][i] * acc[mt][nt][i]);
      }
  __syncthreads();
#pragma unroll
  for (int cc = 0; cc < 8; ++cc) {
    int ch = t + cc * 256;
    int c = ch >> 4, c16 = ch & 15;
    *(bf16x8*)&ZT[(size_t)c * ldz + r0 + c16 * 8] = *(const bf16x8*)&lT[c * 136 + c16 * 8];
  }
}

// ---------------- driver ----------------

extern "C" void kernel_launch(void* const* d_in, const int* in_sizes, int n_in,
                              void* d_out, int out_size, void* d_ws, size_t ws_size,
                              hipStream_t stream) {
  (void)in_sizes; (void)n_in; (void)out_size;
  const float* X   = (const float*)d_in[0];
  const float* A   = (const float*)d_in[1];
  const float* Wup = (const float*)d_in[2];
  const float* bup = (const float*)d_in[3];
  const float* W1  = (const float*)d_in[4];
  const float* b1  = (const float*)d_in[5];
  const float* W2  = (const float*)d_in[6];
  const float* b2  = (const float*)d_in[7];

  const size_t ADJ_BYTES = (size_t)M_NODES * M_NODES * 2;
  char* ws = (char*)d_ws;
  size_t off = 0;
  auto alloc = [&](size_t bytes) {
    char* p = ws + off;
    off += (bytes + 255) & ~(size_t)255;
    return p;
  };
  float*          accb    = (float*)alloc(8 * SLICE_ELEMS * 4);                  // 33.5 MB
  unsigned short* Xu      = (unsigned short*)alloc((size_t)M_NODES * DIM * 2);
  unsigned short* ZT      = (unsigned short*)alloc((size_t)DIM * M_NODES * 2);
  unsigned short* XT      = (unsigned short*)alloc((size_t)DIM * N_NODES * 2);
  unsigned short* W1T     = (unsigned short*)alloc(DIM * DIM * 2);
  unsigned short* W2T     = (unsigned short*)alloc(DIM * DIM * 2);
  float*          colsumA = (float*)alloc(N_NODES * 4);
  float*          deg     = (float*)alloc(M_NODES * 4);

  unsigned short* Adj;
  if (ws_size >= off + ADJ_BYTES) Adj = (unsigned short*)(ws + off);
  else                            Adj = (unsigned short*)d_out;  // Adj dead before final write
  unsigned short* Wupb = Adj;   // tile-major W_up aliases Adj (consumed before Adj written)

  unsigned short* XuNew = Xu + (size_t)N_NODES * DIM;

  hipMemsetAsync(colsumA, 0, N_NODES * 4, stream);
  cast_x_kernel<<<N_NODES * DIM / 256, 256, 0, stream>>>(X, Xu, XT);
  cast_wup_kernel<<<((size_t)N_NODES * N_NODES / 4) / 256, 256, 0, stream>>>(
      (const float4*)Wup, Wupb);
  cast_wt_kernel<<<64, 256, 0, stream>>>(W1, W1T);
  cast_wt_kernel<<<64, 256, 0, stream>>>(W2, W2T);

  // new = W_up @ X (+ b_up): 32 row-tiles, 8 k-splits x (16 x 32k)
  agg_kernel<<<dim3(N_NODES / 128, 8), 256, 0, stream>>>(
      Wupb, 32, XT, N_NODES, accb, 16);
  reduce_acc_kernel<<<N_NODES * DIM / 256, 256, 0, stream>>>(
      accb, XuNew, bup, nullptr, nullptr, 0, 8);

  // Adj blocks [[A,A],[A,.]] tile-major + colsum; deg; S0 = sigmoid(new@new^T) -> quadrant (1,1)
  cast_a_kernel<<<dim3(N_NODES / 256, N_NODES / 128), 256, 0, stream>>>(A, Adj, colsumA);
  init_deg_kernel<<<M_NODES / 256, 256, 0, stream>>>(colsumA, deg);
  rebuild_kernel<0><<<dim3(N_NODES / 128, N_NODES / 128), 256, 0, stream>>>(
      XuNew, XuNew, Adj, N_NODES, N_NODES, deg);

  for (int it = 0; it < 3; ++it) {
    // conv1
    yz_kernel<<<M_NODES / 128, 256, 0, stream>>>(Xu, W1T, deg, ZT, M_NODES);
    agg_kernel<<<dim3(M_NODES / 128, 8), 256, 0, stream>>>(
        Adj, 64, ZT, M_NODES, accb, 32);
    reduce_acc_kernel<<<M_NODES * DIM / 256, 256, 0, stream>>>(
        accb, Xu, nullptr, b1, deg, 1, 8);
    // mid-loop Adj rebuild + deg
    hipMemsetAsync(deg, 0, M_NODES * 4, stream);
    rebuild_kernel<0><<<dim3(M_NODES / 128, M_NODES / 128), 256, 0, stream>>>(
        Xu, Xu, Adj, 0, 0, deg);
    // conv2
    yz_kernel<<<M_NODES / 128, 256, 0, stream>>>(Xu, W2T, deg, ZT, M_NODES);
    agg_kernel<<<dim3(M_NODES / 128, 8), 256, 0, stream>>>(
        Adj, 64, ZT, M_NODES, accb, 32);
    reduce_acc_kernel<<<M_NODES * DIM / 256, 256, 0, stream>>>(
        accb, Xu, nullptr, b2, deg, 1, 8);
    if (it == 2)
      rebuild_kernel<1><<<dim3(M_NODES / 128, M_NODES / 128), 256, 0, stream>>>(
          Xu, Xu, d_out, M_NODES, 0, nullptr);
  }
}

// Round 7
// 989.556 us; speedup vs baseline: 1.2732x; 1.2732x over previous
//
#include <hip/hip_runtime.h>
#include <hip/hip_bf16.h>

// GraphUpsampler: N=4096 -> M=8192 dense GCN, 3 iters, out = sigmoid(Xu@Xu.T) f32 [8192,8192].
// R7: R5 structure (LDS-staged agg, stage-tiled Adj) with 64-ROW agg tiles:
//   grid 1024 -> 4 blocks/CU (16 waves/CU) so per-iter vmcnt(0) drains overlap via TLP.
//   Layout: addr(i,k) = ((i>>6)*KC + (k>>5))*2048 + (i&63)*32 + (k&31), stage = 4KB.

#define N_NODES 4096
#define M_NODES 8192
#define DIM 128
#define SLICE_ELEMS ((size_t)M_NODES * DIM)

typedef __attribute__((ext_vector_type(4))) float f32x4;
typedef __attribute__((ext_vector_type(8))) short bf16x8;

__device__ __forceinline__ unsigned short f2bf(float f) {
  union { float f; unsigned u; } v; v.f = f;
  unsigned r = v.u + 0x7fffu + ((v.u >> 16) & 1u);
  return (unsigned short)(r >> 16);
}

__device__ __forceinline__ void gld16(unsigned short* lds, const unsigned short* g) {
  __builtin_amdgcn_global_load_lds(
      (const __attribute__((address_space(1))) unsigned int*)g,
      (__attribute__((address_space(3))) unsigned int*)lds, 16, 0, 0);
}

__device__ __forceinline__ float sigmoidf_(float x) { return 1.0f / (1.0f + __expf(-x)); }

// ---------------- cast / init kernels ----------------

__global__ void cast_x_kernel(const float* __restrict__ X, unsigned short* __restrict__ Xu,
                              unsigned short* __restrict__ XT) {
  int idx = blockIdx.x * 256 + threadIdx.x;          // N*DIM
  int i = idx >> 7, c = idx & 127;
  unsigned short b = f2bf(X[idx]);
  Xu[idx] = b;
  XT[(size_t)c * N_NODES + i] = b;                   // X^T [128][4096]
}

// W_up f32 [4096][4096] -> bf16 stage-tiled-64 (KC=128)
__global__ void cast_wup_kernel(const float4* __restrict__ W, unsigned short* __restrict__ Wb) {
  int idx4 = blockIdx.x * 256 + threadIdx.x;         // N*N/4
  int r = idx4 >> 10, c = (idx4 & 1023) << 2;
  float4 v = W[idx4];
  ushort4 o;
  o.x = f2bf(v.x); o.y = f2bf(v.y); o.z = f2bf(v.z); o.w = f2bf(v.w);
  *(ushort4*)&Wb[((size_t)(r >> 6) * 128 + (c >> 5)) * 2048 + (r & 63) * 32 + (c & 31)] = o;
}

__global__ void cast_wt_kernel(const float* __restrict__ W, unsigned short* __restrict__ WT) {
  int idx = blockIdx.x * 256 + threadIdx.x;          // 128*128
  int k = idx >> 7, c = idx & 127;
  WT[c * DIM + k] = f2bf(W[idx]);                    // W^T [out][in]
}

// A f32 -> 3 blocks of stage-tiled-64 Adj (KC=256), A symmetric; + colsum(A)
__global__ void cast_a_kernel(const float* __restrict__ A, unsigned short* __restrict__ Adj,
                              float* __restrict__ colsumA) {
  int c = blockIdx.x * 256 + threadIdx.x;            // 0..4095
  int r0 = blockIdx.y * 128;
  size_t cb = (size_t)(c >> 5) * 2048 + (c & 31);
  float s = 0.f;
  for (int r = 0; r < 128; ++r) {
    int i = r0 + r;
    float a = A[(size_t)i * N_NODES + c];
    unsigned short b = f2bf(a);
    size_t rt = (size_t)(i >> 6) * 256 * 2048 + (size_t)(i & 63) * 32;
    Adj[rt + cb] = b;                                   // (i, c)
    Adj[rt + cb + (size_t)128 * 2048] = b;              // (i, 4096+c)
    Adj[rt + (size_t)64 * 256 * 2048 + cb] = b;         // (4096+i, c)
    s += a;
  }
  atomicAdd(&colsumA[c], s);
}

__global__ void init_deg_kernel(const float* __restrict__ colsumA, float* __restrict__ deg) {
  int i = blockIdx.x * 256 + threadIdx.x;            // 8192
  deg[i] = (i < N_NODES) ? 2.0f * colsumA[i] : colsumA[i - N_NODES];
}

// ---------------- LDS-staged split-K aggregation, 64-row tiles ----------------
// C_partial[slice by] = At(stage-tiled)[64 rows bx][32k chunks] @ B (BT[128 n][ldb k]).
// grid (M/64, 8) -> 4 blocks/CU: per-iter barrier drains overlap across blocks.

__global__ __launch_bounds__(256)
void agg_kernel(const unsigned short* __restrict__ At, int kChunksTotal,
                const unsigned short* __restrict__ BT, long ldb,
                float* __restrict__ accBase, int kIters) {
  __shared__ __align__(16) unsigned short lA[2048];   // [64 r][32 k] = 4KB
  __shared__ __align__(16) unsigned short lB[4096];   // [128 n][32 k] = 8KB
  const int t = threadIdx.x, w = t >> 6, lane = t & 63;
  const int q = lane >> 4, l15 = lane & 15;
  const int sg0 = blockIdx.y * kIters;
  const size_t abase = ((size_t)blockIdx.x * kChunksTotal + sg0) * 2048;
  const size_t bk = (size_t)sg0 * 32;
  const int brow = t >> 2, bchk = t & 3;

  f32x4 acc[8];
#pragma unroll
  for (int b = 0; b < 8; ++b) acc[b] = (f32x4)0.f;

  for (int s = 0; s < kIters; ++s) {
    __syncthreads();
    gld16(&lA[t * 8], &At[abase + (size_t)s * 2048 + t * 8]);
    gld16(&lB[t * 8], &BT[(size_t)brow * ldb + bk + s * 32 + bchk * 8]);
    gld16(&lB[2048 + t * 8], &BT[(size_t)(64 + brow) * ldb + bk + s * 32 + bchk * 8]);
    __syncthreads();
    bf16x8 a0 = *(const bf16x8*)&lA[(w * 16 + l15) * 32 + q * 8];
#pragma unroll
    for (int nt = 0; nt < 8; ++nt) {
      bf16x8 b = *(const bf16x8*)&lB[(nt * 16 + l15) * 32 + q * 8];
      acc[nt] = __builtin_amdgcn_mfma_f32_16x16x32_bf16(a0, b, acc[nt], 0, 0, 0);
    }
  }
  // packed C: block = 32KB contiguous, 16B/lane coalesced
  float* ct = accBase + (size_t)blockIdx.y * SLICE_ELEMS + (size_t)blockIdx.x * 8192;
#pragma unroll
  for (int nt = 0; nt < 8; ++nt)
    *(f32x4*)&ct[(w * 8 + nt) * 256 + (q * 16 + l15) * 4] = acc[nt];
}

// sum packed partials + epilogue -> bf16 row-major
// mode 0: v = s + bias_row[row];  mode 1: v = relu(rsqrt(deg[row])*s + bias_col[col])
__global__ void reduce_acc_kernel(const float* __restrict__ acc,
                                  unsigned short* __restrict__ dst,
                                  const float* __restrict__ bias_row,
                                  const float* __restrict__ bias_col,
                                  const float* __restrict__ deg, int mode, int nSlices) {
  int p = blockIdx.x * 256 + threadIdx.x;
  float s = 0.f;
  for (int sp = 0; sp < nSlices; ++sp) s += acc[(size_t)sp * SLICE_ELEMS + p];
  int tile = p >> 13, r = p & 8191;
  int grp = r >> 8, r2 = r & 255;
  int w = grp >> 3, nt = grp & 7;
  int i = r2 & 3, ql = r2 >> 2;
  int row = tile * 64 + w * 16 + (ql >> 4) * 4 + i;
  int col = nt * 16 + (ql & 15);
  float v;
  if (mode == 0) v = s + bias_row[row];
  else {
    float d = deg[row];
    float dv = d > 0.f ? rsqrtf(d) : 0.f;
    v = fmaxf(dv * s + bias_col[col], 0.f);
  }
  dst[(size_t)row * DIM + col] = f2bf(v);
}

// ---------------- rebuild: out = sigmoid(XA @ XB^T), K=128 ----------------
// MODE 0: bf16 stage-tiled-64 out (KC=256) + fused col-sums into deg.
// MODE 1: f32 row-major out (final), repacked via LDS for f32x4 row stores.

template <int MODE>
__global__ __launch_bounds__(256)
void rebuild_kernel(const unsigned short* __restrict__ XA,
                    const unsigned short* __restrict__ XB,
                    void* __restrict__ out, long p1 /*MODE0:row0, MODE1:ldo*/,
                    long col0, float* __restrict__ deg) {
  __shared__ __align__(16) unsigned short smem[32768];   // 64KB
  __shared__ float lcol[128];
  unsigned short* lA = smem;
  unsigned short* lB = smem + 16384;
  const int t = threadIdx.x, w = t >> 6, lane = t & 63;
  const int q = lane >> 4, l15 = lane & 15;
  const int i0 = blockIdx.x * 128, j0 = blockIdx.y * 128;
  const int srow = t >> 2, schk = t & 3;
#pragma unroll
  for (int kk = 0; kk < 4; ++kk)
#pragma unroll
    for (int h = 0; h < 2; ++h) {
      gld16(&lA[kk * 4096 + h * 2048 + t * 8],
            &XA[(size_t)(i0 + h * 64 + srow) * DIM + kk * 32 + schk * 8]);
      gld16(&lB[kk * 4096 + h * 2048 + t * 8],
            &XB[(size_t)(j0 + h * 64 + srow) * DIM + kk * 32 + schk * 8]);
    }
  if (MODE == 0 && t < 128) lcol[t] = 0.f;
  __syncthreads();

  f32x4 acc[2][8];
#pragma unroll
  for (int a = 0; a < 2; ++a)
#pragma unroll
    for (int b = 0; b < 8; ++b) acc[a][b] = (f32x4)0.f;

#pragma unroll
  for (int kk = 0; kk < 4; ++kk) {
    bf16x8 a0 = *(const bf16x8*)&lA[kk * 4096 + (w * 32 + l15) * 32 + q * 8];
    bf16x8 a1 = *(const bf16x8*)&lA[kk * 4096 + (w * 32 + 16 + l15) * 32 + q * 8];
#pragma unroll
    for (int nt = 0; nt < 8; ++nt) {
      bf16x8 b = *(const bf16x8*)&lB[kk * 4096 + (nt * 16 + l15) * 32 + q * 8];
      acc[0][nt] = __builtin_amdgcn_mfma_f32_16x16x32_bf16(a0, b, acc[0][nt], 0, 0, 0);
      acc[1][nt] = __builtin_amdgcn_mfma_f32_16x16x32_bf16(a1, b, acc[1][nt], 0, 0, 0);
    }
  }
  __syncthreads();   // staging reads done; smem reusable

  if (MODE == 0) {
    unsigned short* lC = smem;   // [128][136] bf16
#pragma unroll
    for (int mt = 0; mt < 2; ++mt)
#pragma unroll
      for (int nt = 0; nt < 8; ++nt) {
        float cs = 0.f;
#pragma unroll
        for (int i = 0; i < 4; ++i) {
          float sv = sigmoidf_(acc[mt][nt][i]);
          cs += sv;
          lC[(w * 32 + mt * 16 + q * 4 + i) * 136 + nt * 16 + l15] = f2bf(sv);
        }
        cs += __shfl_xor(cs, 16);
        cs += __shfl_xor(cs, 32);
        if (lane < 16) atomicAdd(&lcol[nt * 16 + lane], cs);
      }
    __syncthreads();
    // stage-tiled-64 store: per (row64, kchunk) 16B chunks, 4KB stages
    unsigned short* og = (unsigned short*)out;
    const long rowbase = p1 + i0, colbase = col0 + j0;
    const size_t tb = ((size_t)(rowbase >> 6) * 256 + (colbase >> 5)) * 2048;
#pragma unroll
    for (int cc = 0; cc < 8; ++cc) {
      int ch = t + cc * 256;                     // 0..2047
      int row = ch >> 4, c16 = ch & 15;
      *(bf16x8*)&og[tb + (size_t)(row >> 6) * 256 * 2048 + (size_t)(c16 >> 2) * 2048 +
                    (row & 63) * 32 + (c16 & 3) * 8] =
          *(const bf16x8*)&lC[row * 136 + c16 * 8];
    }
    if (t < 128) atomicAdd(&deg[colbase + t], lcol[t]);
  } else {
    float* og = (float*)out;
    float* lCf = (float*)smem;                   // [64][128] f32 = 32KB
#pragma unroll
    for (int h2 = 0; h2 < 2; ++h2) {
      __syncthreads();
      if ((w >> 1) == h2) {
#pragma unroll
        for (int mt = 0; mt < 2; ++mt)
#pragma unroll
          for (int nt = 0; nt < 8; ++nt)
#pragma unroll
            for (int i = 0; i < 4; ++i)
              lCf[((w & 1) * 32 + mt * 16 + q * 4 + i) * 128 + nt * 16 + l15] =
                  sigmoidf_(acc[mt][nt][i]);
      }
      __syncthreads();
#pragma unroll
      for (int j = 0; j < 8; ++j) {
        int ch = t + j * 256;                    // f32x4 units
        int r64 = ch >> 5, c4 = (ch & 31) * 4;
        *(f32x4*)&og[(size_t)(i0 + h2 * 64 + r64) * p1 + j0 + c4] =
            *(const f32x4*)&lCf[r64 * 128 + c4];
      }
    }
  }
}

// ---------------- Z^T = (rsqrt(deg) ⊙ (Xu @ W)) transposed, [128][8192] ----------------

__global__ __launch_bounds__(256)
void yz_kernel(const unsigned short* __restrict__ Xu, const unsigned short* __restrict__ WT,
               const float* __restrict__ deg, unsigned short* __restrict__ ZT, int ldz) {
  __shared__ __align__(16) unsigned short smem[32768];
  unsigned short* lA = smem;
  unsigned short* lB = smem + 16384;
  const int t = threadIdx.x, w = t >> 6, lane = t & 63;
  const int q = lane >> 4, l15 = lane & 15;
  const int r0 = blockIdx.x * 128;
  const int srow = t >> 2, schk = t & 3;
#pragma unroll
  for (int kk = 0; kk < 4; ++kk)
#pragma unroll
    for (int h = 0; h < 2; ++h) {
      gld16(&lA[kk * 4096 + h * 2048 + t * 8],
            &Xu[(size_t)(r0 + h * 64 + srow) * DIM + kk * 32 + schk * 8]);
      gld16(&lB[kk * 4096 + h * 2048 + t * 8],
            &WT[(size_t)(h * 64 + srow) * DIM + kk * 32 + schk * 8]);
    }
  __syncthreads();

  f32x4 acc[2][8];
#pragma unroll
  for (int a = 0; a < 2; ++a)
#pragma unroll
    for (int b = 0; b < 8; ++b) acc[a][b] = (f32x4)0.f;

#pragma unroll
  for (int kk = 0; kk < 4; ++kk) {
    bf16x8 a0 = *(const bf16x8*)&lA[kk * 4096 + (w * 32 + l15) * 32 + q * 8];
    bf16x8 a1 = *(const bf16x8*)&lA[kk * 4096 + (w * 32 + 16 + l15) * 32 + q * 8];
#pragma unroll
    for (int nt = 0; nt < 8; ++nt) {
      bf16x8 b = *(const bf16x8*)&lB[kk * 4096 + (nt * 16 + l15) * 32 + q * 8];
      acc[0][nt] = __builtin_amdgcn_mfma_f32_16x16x32_bf16(a0, b, acc[0][nt], 0, 0, 0);
      acc[1][nt] = __builtin_amdgcn_mfma_f32_16x16x32_bf16(a1, b, acc[1][nt], 0, 0, 0);
    }
  }
  float dv[2][4];
#pragma unroll
  for (int mt = 0; mt < 2; ++mt)
#pragma unroll
    for (int i = 0; i < 4; ++i) {
      float d = deg[r0 + w * 32 + mt * 16 + q * 4 + i];
      dv[mt][i] = d > 0.f ? rsqrtf(d) : 0.f;
    }
  __syncthreads();
  unsigned short* lT = smem;   // [c 128][r 136]
#pragma unroll
  for (int mt = 0; mt < 2; ++mt)
#pragma unroll
    for (int nt = 0; nt < 8; ++nt)
#pragma unroll
      for (int i = 0; i < 4; ++i) {
        int r = w * 32 + mt * 16 + q * 4 + i;
        lT[(nt * 16 + l15) * 136 + r] = f2bf(dv[mt][i] * acc[mt][nt][i]);
      }
  __syncthreads();
#pragma unroll
  for (int cc = 0; cc < 8; ++cc) {
    int ch = t + cc * 256;
    int c = ch >> 4, c16 = ch & 15;
    *(bf16x8*)&ZT[(size_t)c * ldz + r0 + c16 * 8] = *(const bf16x8*)&lT[c * 136 + c16 * 8];
  }
}

// ---------------- driver ----------------

extern "C" void kernel_launch(void* const* d_in, const int* in_sizes, int n_in,
                              void* d_out, int out_size, void* d_ws, size_t ws_size,
                              hipStream_t stream) {
  (void)in_sizes; (void)n_in; (void)out_size;
  const float* X   = (const float*)d_in[0];
  const float* A   = (const float*)d_in[1];
  const float* Wup = (const float*)d_in[2];
  const float* bup = (const float*)d_in[3];
  const float* W1  = (const float*)d_in[4];
  const float* b1  = (const float*)d_in[5];
  const float* W2  = (const float*)d_in[6];
  const float* b2  = (const float*)d_in[7];

  const size_t ADJ_BYTES = (size_t)M_NODES * M_NODES * 2;
  char* ws = (char*)d_ws;
  size_t off = 0;
  auto alloc = [&](size_t bytes) {
    char* p = ws + off;
    off += (bytes + 255) & ~(size_t)255;
    return p;
  };
  float*          accb    = (float*)alloc(8 * SLICE_ELEMS * 4);                  // 33.5 MB
  unsigned short* Xu      = (unsigned short*)alloc((size_t)M_NODES * DIM * 2);
  unsigned short* ZT      = (unsigned short*)alloc((size_t)DIM * M_NODES * 2);
  unsigned short* XT      = (unsigned short*)alloc((size_t)DIM * N_NODES * 2);
  unsigned short* W1T     = (unsigned short*)alloc(DIM * DIM * 2);
  unsigned short* W2T     = (unsigned short*)alloc(DIM * DIM * 2);
  float*          colsumA = (float*)alloc(N_NODES * 4);
  float*          deg     = (float*)alloc(M_NODES * 4);

  unsigned short* Adj;
  if (ws_size >= off + ADJ_BYTES) Adj = (unsigned short*)(ws + off);
  else                            Adj = (unsigned short*)d_out;  // Adj dead before final write
  unsigned short* Wupb = Adj;   // stage-tiled W_up aliases Adj (consumed before Adj written)

  unsigned short* XuNew = Xu + (size_t)N_NODES * DIM;

  hipMemsetAsync(colsumA, 0, N_NODES * 4, stream);
  cast_x_kernel<<<N_NODES * DIM / 256, 256, 0, stream>>>(X, Xu, XT);
  cast_wup_kernel<<<((size_t)N_NODES * N_NODES / 4) / 256, 256, 0, stream>>>(
      (const float4*)Wup, Wupb);
  cast_wt_kernel<<<64, 256, 0, stream>>>(W1, W1T);
  cast_wt_kernel<<<64, 256, 0, stream>>>(W2, W2T);

  // new = W_up @ X (+ b_up): KC=128, grid (64, 8), kIters=16
  agg_kernel<<<dim3(N_NODES / 64, 8), 256, 0, stream>>>(
      Wupb, 128, XT, N_NODES, accb, 16);
  reduce_acc_kernel<<<N_NODES * DIM / 256, 256, 0, stream>>>(
      accb, XuNew, bup, nullptr, nullptr, 0, 8);

  // Adj blocks [[A,A],[A,.]] stage-tiled + colsum; deg; S0 -> quadrant (1,1)
  cast_a_kernel<<<dim3(N_NODES / 256, N_NODES / 128), 256, 0, stream>>>(A, Adj, colsumA);
  init_deg_kernel<<<M_NODES / 256, 256, 0, stream>>>(colsumA, deg);
  rebuild_kernel<0><<<dim3(N_NODES / 128, N_NODES / 128), 256, 0, stream>>>(
      XuNew, XuNew, Adj, N_NODES, N_NODES, deg);

  for (int it = 0; it < 3; ++it) {
    // conv1
    yz_kernel<<<M_NODES / 128, 256, 0, stream>>>(Xu, W1T, deg, ZT, M_NODES);
    agg_kernel<<<dim3(M_NODES / 64, 8), 256, 0, stream>>>(
        Adj, 256, ZT, M_NODES, accb, 32);
    reduce_acc_kernel<<<M_NODES * DIM / 256, 256, 0, stream>>>(
        accb, Xu, nullptr, b1, deg, 1, 8);
    // mid-loop Adj rebuild + deg
    hipMemsetAsync(deg, 0, M_NODES * 4, stream);
    rebuild_kernel<0><<<dim3(M_NODES / 128, M_NODES / 128), 256, 0, stream>>>(
        Xu, Xu, Adj, 0, 0, deg);
    // conv2
    yz_kernel<<<M_NODES / 128, 256, 0, stream>>>(Xu, W2T, deg, ZT, M_NODES);
    agg_kernel<<<dim3(M_NODES / 64, 8), 256, 0, stream>>>(
        Adj, 256, ZT, M_NODES, accb, 32);
    reduce_acc_kernel<<<M_NODES * DIM / 256, 256, 0, stream>>>(
        accb, Xu, nullptr, b2, deg, 1, 8);
    if (it == 2)
      rebuild_kernel<1><<<dim3(M_NODES / 128, M_NODES / 128), 256, 0, stream>>>(
          Xu, Xu, d_out, M_NODES, 0, nullptr);
  }
}